// Round 2
// baseline (563.162 us; speedup 1.0000x reference)
//
#include <hip/hip_runtime.h>
#include <hip/hip_bf16.h>

#define B_ROWS   4096
#define L_LABELS 100000
#define L_PAD    100032   // 1563 * 64, padded with zero rows
#define PADROWS  32       // L_PAD - L_LABELS
#define D_DIM    256
#define TOPK     5
#define SLABN    64       // labels per slab
#define NSLAB    1563     // L_PAD / SLABN
#define NGROUP   8        // N-groups == XCD count
#define SLABBYTES 32768   // SLABN * D_DIM * 2

typedef __bf16 bf16x8 __attribute__((ext_vector_type(8)));
typedef __bf16 bf16x4 __attribute__((ext_vector_type(4)));
typedef float  f32x4  __attribute__((ext_vector_type(4)));

__device__ __forceinline__ void async16(const void* g, void* l) {
    __builtin_amdgcn_global_load_lds(
        (const __attribute__((address_space(1))) unsigned int*)g,
        (__attribute__((address_space(3))) unsigned int*)l,
        16, 0, 0);
}

// ---------------------------------------------------------------------------
// fp32 -> bf16 converters
// ---------------------------------------------------------------------------
__global__ void convertP_kernel(const float* __restrict__ src,
                                __hip_bfloat16* __restrict__ dst) {
    size_t i = ((size_t)blockIdx.x * blockDim.x + threadIdx.x) * 8;
    float4 a = *(const float4*)(src + i);
    float4 b = *(const float4*)(src + i + 4);
    bf16x8 v = {(__bf16)a.x, (__bf16)a.y, (__bf16)a.z, (__bf16)a.w,
                (__bf16)b.x, (__bf16)b.y, (__bf16)b.z, (__bf16)b.w};
    *(bf16x8*)((__bf16*)dst + i) = v;
}

__global__ void convertL_kernel(const float* __restrict__ src,
                                __hip_bfloat16* __restrict__ dst) {
    size_t i = ((size_t)blockIdx.x * blockDim.x + threadIdx.x) * 8;
    bf16x8 v;
    if (i < (size_t)L_LABELS * D_DIM) {
        float4 a = *(const float4*)(src + i);
        float4 b = *(const float4*)(src + i + 4);
        v = (bf16x8){(__bf16)a.x, (__bf16)a.y, (__bf16)a.z, (__bf16)a.w,
                     (__bf16)b.x, (__bf16)b.y, (__bf16)b.z, (__bf16)b.w};
    } else {
        v = (bf16x8){(__bf16)0.f, (__bf16)0.f, (__bf16)0.f, (__bf16)0.f,
                     (__bf16)0.f, (__bf16)0.f, (__bf16)0.f, (__bf16)0.f};
    }
    *(bf16x8*)((__bf16*)dst + i) = v;
}

// ---------------------------------------------------------------------------
// Kernel 1: per-row threshold s_t (bf16-rounded inputs) + zero counters.
// ---------------------------------------------------------------------------
__global__ void prep_kernel(const float* __restrict__ P,
                            const float* __restrict__ Lab,
                            const int*   __restrict__ labels,
                            float* __restrict__ s_t,
                            int*   __restrict__ counts) {
    int gwave = (blockIdx.x * blockDim.x + threadIdx.x) >> 6;
    int lane  = threadIdx.x & 63;
    if (gwave >= B_ROWS) return;
    int t = labels[gwave];
    const float4* p4 = (const float4*)(P + (size_t)gwave * D_DIM);
    const float4* l4 = (const float4*)(Lab + (size_t)t * D_DIM);
    float4 a = p4[lane];
    float4 b = l4[lane];
    float sum = 0.f;
    sum += (float)(__bf16)a.x * (float)(__bf16)b.x;
    sum += (float)(__bf16)a.y * (float)(__bf16)b.y;
    sum += (float)(__bf16)a.z * (float)(__bf16)b.z;
    sum += (float)(__bf16)a.w * (float)(__bf16)b.w;
    #pragma unroll
    for (int m = 1; m < 64; m <<= 1) sum += __shfl_xor(sum, m, 64);
    if (lane == 0) {
        s_t[gwave]    = sum;
        counts[gwave] = 0;
    }
}

// ---------------------------------------------------------------------------
// Kernel 2 (v5): A-in-registers / B-DMA-streaming count GEMM.
// v4 -> v5: replace the 2-buffer __syncthreads() loop (which drains
// vmcnt(0) every slab, exposing the full DMA latency of the just-issued
// prefetch) with a 4-deep LDS ring + counted s_waitcnt vmcnt(8) + raw
// s_barrier (T3/T4). Two slabs' loads (8 per wave) stay in flight across
// every barrier; prefetch distance is 3 slabs. Tail iterations step the
// wait down 8 -> 4 -> 0. Loop-body VMEM is exactly the 4 DMA intrinsics,
// so the counted waits are exact in steady state (and merely over-wait if
// the compiler reorders prologue loads -- monotone-safe).
// Buffer-reuse safety: slab s+3 is written into buf (it+3)&3 = (it-1)&3,
// which all waves finished ds_reading before the iteration-it barrier
// (enforced by the lgkmcnt(0) in the wait).
// ---------------------------------------------------------------------------
#define CBM 128

__global__ __launch_bounds__(512, 2)
void count_kernel_v5(const __hip_bfloat16* __restrict__ Pb,
                     const __hip_bfloat16* __restrict__ Lb,
                     const int*   __restrict__ labels,
                     const float* __restrict__ s_t,
                     int* __restrict__ counts) {
    __shared__ __align__(16) __bf16 Bs[4 * SLABN * D_DIM];   // 4 x 32 KB ring

    const int group = blockIdx.x;          // 0..7 -> XCD via %8 dispatch
    const int Mbase = blockIdx.y * CBM;
    const int tid   = threadIdx.x;
    const int wave  = tid >> 6;            // 0..7
    const int lane  = tid & 63;
    const int wm    = wave >> 2;           // 0..1 : 64-row half
    const int wn    = wave & 3;            // 0..3 : 16-label quarter
    const int quad  = lane >> 4;           // 0..3
    const int cc    = lane & 15;           // 0..15

    const int s0 = (group * NSLAB) / NGROUP;
    const int s1 = ((group + 1) * NSLAB) / NGROUP;
    const int nslab = s1 - s0;

    // per-thread DMA source offsets (bytes within a slab) + LDS wave bases
    int dma_off[4];
    #pragma unroll
    for (int j = 0; j < 4; ++j) {
        int q   = j * 512 + tid;       // chunk slot 0..2047
        int row = q >> 5;              // label row 0..63
        int qc  = q & 31;              // chunk col in row
        int gc  = (qc & 24) | ((qc ^ row) & 7);
        dma_off[j] = row * 512 + gc * 16;
    }

    const char* gslab0 = (const char*)Lb + (size_t)s0 * SLABBYTES;

    // ---- prologue: slab 0 DMA first (oldest in vmcnt order) ----
    #pragma unroll
    for (int j = 0; j < 4; ++j)
        async16(gslab0 + dma_off[j],
                (char*)Bs + (size_t)(j * 512 + wave * 64) * 16);

    // ---- load stationary A fragments: 64 rows x K=256 per wave ----
    bf16x8 af[4][8];
    #pragma unroll
    for (int mi = 0; mi < 4; ++mi) {
        int row = Mbase + wm * 64 + mi * 16 + cc;
        const __bf16* ap = (const __bf16*)Pb + (size_t)row * D_DIM + quad * 8;
        #pragma unroll
        for (int kb = 0; kb < 8; ++kb)
            af[mi][kb] = *(const bf16x8*)(ap + kb * 32);
    }

    // ---- per-row threshold / label (C/D rows: quad*4 + r) ----
    float sr[4][4];
    int   tr[4][4];
    #pragma unroll
    for (int mi = 0; mi < 4; ++mi)
        #pragma unroll
        for (int r = 0; r < 4; ++r) {
            int row = Mbase + wm * 64 + mi * 16 + quad * 4 + r;
            sr[mi][r] = s_t[row];
            tr[mi][r] = labels[row];
        }

    // ---- prologue: slabs 1,2 issued last, so they are the newest
    //      (exactly the 8 loads vmcnt(8) leaves in flight at iteration 0) ----
    #pragma unroll
    for (int p = 1; p <= 2; ++p) {
        if (p < nslab) {
            const char* g = gslab0 + (size_t)p * SLABBYTES;
            char* l = (char*)Bs + (size_t)p * SLABBYTES;
            #pragma unroll
            for (int j = 0; j < 4; ++j)
                async16(g + dma_off[j],
                        l + (size_t)(j * 512 + wave * 64) * 16);
        }
    }

    int cnt[4][4] = {};

    for (int it = 0; it < nslab; ++it) {
        const int s   = s0 + it;
        const int rem = nslab - 1 - it;   // slabs issued beyond s (cap 2)

        // counted wait: slab s's 4 loads landed; up to 2 newer slabs in flight.
        if (rem >= 2)      asm volatile("s_waitcnt vmcnt(8) lgkmcnt(0)" ::: "memory");
        else if (rem == 1) asm volatile("s_waitcnt vmcnt(4) lgkmcnt(0)" ::: "memory");
        else               asm volatile("s_waitcnt vmcnt(0) lgkmcnt(0)" ::: "memory");
        __builtin_amdgcn_s_barrier();
        __builtin_amdgcn_sched_barrier(0);

        // issue slab s+3 into the buffer read in iteration it-1
        if (it + 3 < nslab) {
            const char* g = gslab0 + (size_t)(it + 3) * SLABBYTES;
            char* l = (char*)Bs + (size_t)((it + 3) & 3) * SLABBYTES;
            #pragma unroll
            for (int j = 0; j < 4; ++j)
                async16(g + dma_off[j],
                        l + (size_t)(j * 512 + wave * 64) * 16);
        }

        const __bf16* bp = Bs + (size_t)(it & 3) * (SLABN * D_DIM);

        f32x4 acc[4] = {};
        #pragma unroll
        for (int kb = 0; kb < 8; ++kb) {
            int ci = kb * 4 + quad;
            int qc = (ci & 24) | ((ci ^ cc) & 7);   // col&7 == cc&7
            bf16x8 b = *(const bf16x8*)&bp[(wn * 16 + cc) * D_DIM + qc * 8];
            #pragma unroll
            for (int mi = 0; mi < 4; ++mi)
                acc[mi] = __builtin_amdgcn_mfma_f32_16x16x32_bf16(
                    af[mi][kb], b, acc[mi], 0, 0, 0);
        }

        // epilogue: accumulate beat counts in registers
        int nb = s * SLABN + wn * 16;
        int n  = nb + cc;
        #pragma unroll
        for (int mi = 0; mi < 4; ++mi)
            #pragma unroll
            for (int r = 0; r < 4; ++r) {
                float sv = acc[mi][r];
                bool beat = (n != tr[mi][r]) &&
                            (sv > sr[mi][r] ||
                             (sv == sr[mi][r] && n < tr[mi][r]));
                cnt[mi][r] += beat ? 1 : 0;
            }
    }

    // ---- reduce over the 16 cc lanes, one atomic per (wave, quad, mi, r) ----
    #pragma unroll
    for (int mi = 0; mi < 4; ++mi)
        #pragma unroll
        for (int r = 0; r < 4; ++r) {
            int v = cnt[mi][r];
            v += __shfl_xor(v, 1, 64);
            v += __shfl_xor(v, 2, 64);
            v += __shfl_xor(v, 4, 64);
            v += __shfl_xor(v, 8, 64);
            if (cc == 0) {
                int row = Mbase + wm * 64 + mi * 16 + quad * 4 + r;
                atomicAdd(&counts[row], v);
            }
        }
}

// ---------------------------------------------------------------------------
// Kernel 2 (fallback, R1 path) — only if ws too small for bf16 copies.
// ---------------------------------------------------------------------------
#define FBM 128
#define FBN 128
#define FBK 32
#define KPAD 40

__global__ __launch_bounds__(256)
void count_kernel_slow(const float* __restrict__ P,
                       const float* __restrict__ Lab,
                       const int*   __restrict__ labels,
                       const float* __restrict__ s_t,
                       int* __restrict__ counts) {
    __shared__ __align__(16) __bf16 As[FBM][KPAD];
    __shared__ __align__(16) __bf16 Bs[FBN][KPAD];

    const int Nbase = blockIdx.x * FBN;
    const int Mbase = blockIdx.y * FBM;
    const int tid  = threadIdx.x;
    const int lane = tid & 63;
    const int wave = tid >> 6;
    const int wm = wave >> 1;
    const int wn = wave & 1;
    const int quad = lane >> 4;
    const int c    = lane & 15;

    const int srow  = tid >> 1;
    const int skoff = (tid & 1) * 16;
    const int brow_g = min(Nbase + srow, L_LABELS - 1);

    f32x4 acc[4][4] = {};

    for (int Kb = 0; Kb < D_DIM; Kb += FBK) {
        const float* gA = P   + (size_t)(Mbase + srow) * D_DIM + Kb + skoff;
        const float* gB = Lab + (size_t)brow_g        * D_DIM + Kb + skoff;
        #pragma unroll
        for (int i = 0; i < 4; ++i) {
            float4 va = *(const float4*)(gA + i * 4);
            float4 vb = *(const float4*)(gB + i * 4);
            *(bf16x4*)&As[srow][skoff + i * 4] =
                (bf16x4){(__bf16)va.x, (__bf16)va.y, (__bf16)va.z, (__bf16)va.w};
            *(bf16x4*)&Bs[srow][skoff + i * 4] =
                (bf16x4){(__bf16)vb.x, (__bf16)vb.y, (__bf16)vb.z, (__bf16)vb.w};
        }
        __syncthreads();

        bf16x8 afr[4], bfr[4];
        #pragma unroll
        for (int mi = 0; mi < 4; ++mi)
            afr[mi] = *(const bf16x8*)&As[wm * 64 + mi * 16 + c][quad * 8];
        #pragma unroll
        for (int ni = 0; ni < 4; ++ni)
            bfr[ni] = *(const bf16x8*)&Bs[wn * 64 + ni * 16 + c][quad * 8];

        #pragma unroll
        for (int mi = 0; mi < 4; ++mi)
            #pragma unroll
            for (int ni = 0; ni < 4; ++ni)
                acc[mi][ni] = __builtin_amdgcn_mfma_f32_16x16x32_bf16(
                    afr[mi], bfr[ni], acc[mi][ni], 0, 0, 0);
        __syncthreads();
    }

    #pragma unroll
    for (int mi = 0; mi < 4; ++mi) {
        int rowb = Mbase + wm * 64 + mi * 16 + quad * 4;
        #pragma unroll
        for (int r = 0; r < 4; ++r) {
            int   row = rowb + r;
            float st  = s_t[row];
            int   t   = labels[row];
            int   cnt = 0;
            #pragma unroll
            for (int ni = 0; ni < 4; ++ni) {
                int   n = Nbase + wn * 64 + ni * 16 + c;
                float s = acc[mi][ni][r];
                bool beat = (n < L_LABELS) && (n != t) &&
                            (s > st || (s == st && n < t));
                cnt += beat ? 1 : 0;
            }
            cnt += __shfl_xor(cnt, 1, 64);
            cnt += __shfl_xor(cnt, 2, 64);
            cnt += __shfl_xor(cnt, 4, 64);
            cnt += __shfl_xor(cnt, 8, 64);
            if (c == 0 && cnt) atomicAdd(&counts[row], cnt);
        }
    }
}

// ---------------------------------------------------------------------------
// Kernel 3: accuracy = mean(adjusted_counts[b] < TOPK).
// ---------------------------------------------------------------------------
__global__ void finalize_kernel(const int* __restrict__ counts,
                                const float* __restrict__ s_t,
                                float* __restrict__ out,
                                int pad_correct) {
    __shared__ int sdata[4];
    int tid = threadIdx.x;
    int local = 0;
    for (int i = tid; i < B_ROWS; i += 256) {
        int c = counts[i];
        if (pad_correct && s_t[i] < 0.0f) c -= PADROWS;
        local += (c < TOPK) ? 1 : 0;
    }
    #pragma unroll
    for (int m = 1; m < 64; m <<= 1) local += __shfl_xor(local, m, 64);
    if ((tid & 63) == 0) sdata[tid >> 6] = local;
    __syncthreads();
    if (tid == 0)
        out[0] = (float)(sdata[0] + sdata[1] + sdata[2] + sdata[3]) /
                 (float)B_ROWS;
}

extern "C" void kernel_launch(void* const* d_in, const int* in_sizes, int n_in,
                              void* d_out, int out_size, void* d_ws, size_t ws_size,
                              hipStream_t stream) {
    const float* P      = (const float*)d_in[0];
    const float* Lab    = (const float*)d_in[1];
    const int*   labels = (const int*)d_in[2];
    float* out = (float*)d_out;

    float* s_t    = (float*)d_ws;
    int*   counts = (int*)((char*)d_ws + 16384);

    prep_kernel<<<dim3(B_ROWS / 4), 256, 0, stream>>>(P, Lab, labels, s_t, counts);

    const size_t pb_off = 32768;
    const size_t lb_off = pb_off + (size_t)B_ROWS * D_DIM * 2;  // 2 MB
    const size_t need   = lb_off + (size_t)L_PAD * D_DIM * 2;   // ~51 MB

    int fast = (ws_size >= need) ? 1 : 0;
    if (fast) {
        __hip_bfloat16* Pb = (__hip_bfloat16*)((char*)d_ws + pb_off);
        __hip_bfloat16* Lb = (__hip_bfloat16*)((char*)d_ws + lb_off);
        convertP_kernel<<<dim3((B_ROWS * D_DIM) / 2048), 256, 0, stream>>>(P, Pb);
        convertL_kernel<<<dim3(((size_t)L_PAD * D_DIM) / 2048), 256, 0, stream>>>(Lab, Lb);
        count_kernel_v5<<<dim3(NGROUP, B_ROWS / CBM), 512, 0, stream>>>(
            Pb, Lb, labels, s_t, counts);
    } else {
        dim3 grid((L_LABELS + FBN - 1) / FBN, B_ROWS / FBM);
        count_kernel_slow<<<grid, 256, 0, stream>>>(P, Lab, labels, s_t, counts);
    }

    finalize_kernel<<<1, 256, 0, stream>>>(counts, s_t, out, fast);
}

// Round 3
// 405.134 us; speedup vs baseline: 1.3901x; 1.3901x over previous
//
#include <hip/hip_runtime.h>
#include <hip/hip_bf16.h>

#define B_ROWS   4096
#define L_LABELS 100000
#define L_PAD    100032   // 1563 * 64, padded with zero rows
#define PADROWS  32       // L_PAD - L_LABELS
#define D_DIM    256
#define TOPK     5
#define SLABN    64       // labels per slab
#define NSLAB    1563     // L_PAD / SLABN
#define NGROUP   8        // N-groups == XCD count
#define SLABBYTES 32768   // SLABN * D_DIM * 2

typedef __bf16 bf16x8 __attribute__((ext_vector_type(8)));
typedef __bf16 bf16x4 __attribute__((ext_vector_type(4)));
typedef float  f32x4  __attribute__((ext_vector_type(4)));

__device__ __forceinline__ void async16(const void* g, void* l) {
    __builtin_amdgcn_global_load_lds(
        (const __attribute__((address_space(1))) unsigned int*)g,
        (__attribute__((address_space(3))) unsigned int*)l,
        16, 0, 0);
}

// ---------------------------------------------------------------------------
// fp32 -> bf16 converters
// ---------------------------------------------------------------------------
__global__ void convertP_kernel(const float* __restrict__ src,
                                __hip_bfloat16* __restrict__ dst) {
    size_t i = ((size_t)blockIdx.x * blockDim.x + threadIdx.x) * 8;
    float4 a = *(const float4*)(src + i);
    float4 b = *(const float4*)(src + i + 4);
    bf16x8 v = {(__bf16)a.x, (__bf16)a.y, (__bf16)a.z, (__bf16)a.w,
                (__bf16)b.x, (__bf16)b.y, (__bf16)b.z, (__bf16)b.w};
    *(bf16x8*)((__bf16*)dst + i) = v;
}

__global__ void convertL_kernel(const float* __restrict__ src,
                                __hip_bfloat16* __restrict__ dst) {
    size_t i = ((size_t)blockIdx.x * blockDim.x + threadIdx.x) * 8;
    bf16x8 v;
    if (i < (size_t)L_LABELS * D_DIM) {
        float4 a = *(const float4*)(src + i);
        float4 b = *(const float4*)(src + i + 4);
        v = (bf16x8){(__bf16)a.x, (__bf16)a.y, (__bf16)a.z, (__bf16)a.w,
                     (__bf16)b.x, (__bf16)b.y, (__bf16)b.z, (__bf16)b.w};
    } else {
        v = (bf16x8){(__bf16)0.f, (__bf16)0.f, (__bf16)0.f, (__bf16)0.f,
                     (__bf16)0.f, (__bf16)0.f, (__bf16)0.f, (__bf16)0.f};
    }
    *(bf16x8*)((__bf16*)dst + i) = v;
}

// ---------------------------------------------------------------------------
// Kernel 1: per-row threshold s_t (bf16-rounded inputs) + zero counters.
// ---------------------------------------------------------------------------
__global__ void prep_kernel(const float* __restrict__ P,
                            const float* __restrict__ Lab,
                            const int*   __restrict__ labels,
                            float* __restrict__ s_t,
                            int*   __restrict__ counts) {
    int gwave = (blockIdx.x * blockDim.x + threadIdx.x) >> 6;
    int lane  = threadIdx.x & 63;
    if (gwave >= B_ROWS) return;
    int t = labels[gwave];
    const float4* p4 = (const float4*)(P + (size_t)gwave * D_DIM);
    const float4* l4 = (const float4*)(Lab + (size_t)t * D_DIM);
    float4 a = p4[lane];
    float4 b = l4[lane];
    float sum = 0.f;
    sum += (float)(__bf16)a.x * (float)(__bf16)b.x;
    sum += (float)(__bf16)a.y * (float)(__bf16)b.y;
    sum += (float)(__bf16)a.z * (float)(__bf16)b.z;
    sum += (float)(__bf16)a.w * (float)(__bf16)b.w;
    #pragma unroll
    for (int m = 1; m < 64; m <<= 1) sum += __shfl_xor(sum, m, 64);
    if (lane == 0) {
        s_t[gwave]    = sum;
        counts[gwave] = 0;
    }
}

// ---------------------------------------------------------------------------
// Kernel 2 (v6): A-in-registers / B-DMA-streaming count GEMM.
//
// v5 post-mortem: counted-vmcnt regressed (356->426); counters showed the
// pipes running SERIALLY (MFMA 24% + VALU 36% + LDS ~23% ~= 100%) because
// occupancy is register-bound at 2 waves/SIMD (af[4][8]=128 acc-file regs
// + 112 arch). The barrier drain was never the stall.
//
// v4 -> v6: keep the proven __syncthreads() 2-buffer loop; halve the
// per-wave stationary A tile (32 rows, af[2][8]=64 regs) so a wave fits in
// 128 total regs -> 4 waves/SIMD. CBM=64, grid 8x64=512 blocks = 2
// blocks/CU; co-resident blocks are same-group (same XCD) so they share
// the B slab stream in L2, and their interleaved phases overlap
// MFMA/VALU/LDS across blocks. __launch_bounds__(512,4) enforces the cap.
// ---------------------------------------------------------------------------
#define CBM 64

__global__ __launch_bounds__(512, 4)
void count_kernel_v6(const __hip_bfloat16* __restrict__ Pb,
                     const __hip_bfloat16* __restrict__ Lb,
                     const int*   __restrict__ labels,
                     const float* __restrict__ s_t,
                     int* __restrict__ counts) {
    __shared__ __align__(16) __bf16 Bs[2 * SLABN * D_DIM];   // 2 x 32 KB

    const int group = blockIdx.x;          // 0..7 -> XCD via %8 dispatch
    const int Mbase = blockIdx.y * CBM;
    const int tid   = threadIdx.x;
    const int wave  = tid >> 6;            // 0..7
    const int lane  = tid & 63;
    const int wm    = wave >> 2;           // 0..1 : 32-row half
    const int wn    = wave & 3;            // 0..3 : 16-label quarter
    const int quad  = lane >> 4;           // 0..3
    const int cc    = lane & 15;           // 0..15

    const int s0 = (group * NSLAB) / NGROUP;
    const int s1 = ((group + 1) * NSLAB) / NGROUP;

    // per-thread DMA source offset for j=0; j-th load adds j*8192 bytes.
    // (row = j*16 + tid>>5, qc = tid&31, and row&7 == (tid>>5)&7 for all j,
    //  so the swizzled chunk col gc is j-invariant.)
    const int qc0  = tid & 31;
    const int rw0  = tid >> 5;
    const int gc0  = (qc0 & 24) | ((qc0 ^ rw0) & 7);
    const int dma0 = rw0 * 512 + gc0 * 16;
    const int ldsw = wave * 1024;          // wave-uniform LDS base (bytes)

    // ---- issue DMA for first slab into buffer 0 ----
    {
        const char* gbase = (const char*)Lb + (size_t)s0 * SLABBYTES;
        #pragma unroll
        for (int j = 0; j < 4; ++j)
            async16(gbase + dma0 + j * 8192,
                    (char*)Bs + ldsw + j * 8192);
    }

    // ---- load stationary A fragments: 32 rows x K=256 per wave ----
    bf16x8 af[2][8];
    #pragma unroll
    for (int mi = 0; mi < 2; ++mi) {
        int row = Mbase + wm * 32 + mi * 16 + cc;
        const __bf16* ap = (const __bf16*)Pb + (size_t)row * D_DIM + quad * 8;
        #pragma unroll
        for (int kb = 0; kb < 8; ++kb)
            af[mi][kb] = *(const bf16x8*)(ap + kb * 32);
    }

    // ---- per-row threshold / label (C/D rows: quad*4 + r) ----
    float sr[2][4];
    int   tr[2][4];
    #pragma unroll
    for (int mi = 0; mi < 2; ++mi)
        #pragma unroll
        for (int r = 0; r < 4; ++r) {
            int row = Mbase + wm * 32 + mi * 16 + quad * 4 + r;
            sr[mi][r] = s_t[row];
            tr[mi][r] = labels[row];
        }

    int cnt[2][4] = {};

    for (int s = s0, it = 0; s < s1; ++s, ++it) {
        __syncthreads();   // waits current slab's DMA (vmcnt 0) + buffer reuse

        // issue next slab's DMA into the other buffer; stays in flight
        if (s + 1 < s1) {
            const char* gbase = (const char*)Lb + (size_t)(s + 1) * SLABBYTES;
            char* lbase = (char*)Bs + (size_t)(~it & 1) * SLABBYTES + ldsw;
            #pragma unroll
            for (int j = 0; j < 4; ++j)
                async16(gbase + dma0 + j * 8192, lbase + j * 8192);
        }

        const __bf16* bp = Bs + (size_t)(it & 1) * (SLABN * D_DIM);

        f32x4 acc[2] = {};
        #pragma unroll
        for (int kb = 0; kb < 8; ++kb) {
            int ci = kb * 4 + quad;
            int qc = (ci & 24) | ((ci ^ cc) & 7);   // col&7 == cc&7
            bf16x8 b = *(const bf16x8*)&bp[(wn * 16 + cc) * D_DIM + qc * 8];
            #pragma unroll
            for (int mi = 0; mi < 2; ++mi)
                acc[mi] = __builtin_amdgcn_mfma_f32_16x16x32_bf16(
                    af[mi][kb], b, acc[mi], 0, 0, 0);
        }

        // epilogue: accumulate beat counts in registers
        int n = s * SLABN + wn * 16 + cc;
        #pragma unroll
        for (int mi = 0; mi < 2; ++mi)
            #pragma unroll
            for (int r = 0; r < 4; ++r) {
                float sv = acc[mi][r];
                bool beat = (n != tr[mi][r]) &&
                            (sv > sr[mi][r] ||
                             (sv == sr[mi][r] && n < tr[mi][r]));
                cnt[mi][r] += beat ? 1 : 0;
            }
    }

    // ---- reduce over the 16 cc lanes, one atomic per (wave, quad, mi, r) ----
    #pragma unroll
    for (int mi = 0; mi < 2; ++mi)
        #pragma unroll
        for (int r = 0; r < 4; ++r) {
            int v = cnt[mi][r];
            v += __shfl_xor(v, 1, 64);
            v += __shfl_xor(v, 2, 64);
            v += __shfl_xor(v, 4, 64);
            v += __shfl_xor(v, 8, 64);
            if (cc == 0) {
                int row = Mbase + wm * 32 + mi * 16 + quad * 4 + r;
                atomicAdd(&counts[row], v);
            }
        }
}

// ---------------------------------------------------------------------------
// Kernel 2 (fallback, R1 path) — only if ws too small for bf16 copies.
// ---------------------------------------------------------------------------
#define FBM 128
#define FBN 128
#define FBK 32
#define KPAD 40

__global__ __launch_bounds__(256)
void count_kernel_slow(const float* __restrict__ P,
                       const float* __restrict__ Lab,
                       const int*   __restrict__ labels,
                       const float* __restrict__ s_t,
                       int* __restrict__ counts) {
    __shared__ __align__(16) __bf16 As[FBM][KPAD];
    __shared__ __align__(16) __bf16 Bs[FBN][KPAD];

    const int Nbase = blockIdx.x * FBN;
    const int Mbase = blockIdx.y * FBM;
    const int tid  = threadIdx.x;
    const int lane = tid & 63;
    const int wave = tid >> 6;
    const int wm = wave >> 1;
    const int wn = wave & 1;
    const int quad = lane >> 4;
    const int c    = lane & 15;

    const int srow  = tid >> 1;
    const int skoff = (tid & 1) * 16;
    const int brow_g = min(Nbase + srow, L_LABELS - 1);

    f32x4 acc[4][4] = {};

    for (int Kb = 0; Kb < D_DIM; Kb += FBK) {
        const float* gA = P   + (size_t)(Mbase + srow) * D_DIM + Kb + skoff;
        const float* gB = Lab + (size_t)brow_g        * D_DIM + Kb + skoff;
        #pragma unroll
        for (int i = 0; i < 4; ++i) {
            float4 va = *(const float4*)(gA + i * 4);
            float4 vb = *(const float4*)(gB + i * 4);
            *(bf16x4*)&As[srow][skoff + i * 4] =
                (bf16x4){(__bf16)va.x, (__bf16)va.y, (__bf16)va.z, (__bf16)va.w};
            *(bf16x4*)&Bs[srow][skoff + i * 4] =
                (bf16x4){(__bf16)vb.x, (__bf16)vb.y, (__bf16)vb.z, (__bf16)vb.w};
        }
        __syncthreads();

        bf16x8 afr[4], bfr[4];
        #pragma unroll
        for (int mi = 0; mi < 4; ++mi)
            afr[mi] = *(const bf16x8*)&As[wm * 64 + mi * 16 + c][quad * 8];
        #pragma unroll
        for (int ni = 0; ni < 4; ++ni)
            bfr[ni] = *(const bf16x8*)&Bs[wn * 64 + ni * 16 + c][quad * 8];

        #pragma unroll
        for (int mi = 0; mi < 4; ++mi)
            #pragma unroll
            for (int ni = 0; ni < 4; ++ni)
                acc[mi][ni] = __builtin_amdgcn_mfma_f32_16x16x32_bf16(
                    afr[mi], bfr[ni], acc[mi][ni], 0, 0, 0);
        __syncthreads();
    }

    #pragma unroll
    for (int mi = 0; mi < 4; ++mi) {
        int rowb = Mbase + wm * 64 + mi * 16 + quad * 4;
        #pragma unroll
        for (int r = 0; r < 4; ++r) {
            int   row = rowb + r;
            float st  = s_t[row];
            int   t   = labels[row];
            int   cnt = 0;
            #pragma unroll
            for (int ni = 0; ni < 4; ++ni) {
                int   n = Nbase + wn * 64 + ni * 16 + c;
                float s = acc[mi][ni][r];
                bool beat = (n < L_LABELS) && (n != t) &&
                            (s > st || (s == st && n < t));
                cnt += beat ? 1 : 0;
            }
            cnt += __shfl_xor(cnt, 1, 64);
            cnt += __shfl_xor(cnt, 2, 64);
            cnt += __shfl_xor(cnt, 4, 64);
            cnt += __shfl_xor(cnt, 8, 64);
            if (c == 0 && cnt) atomicAdd(&counts[row], cnt);
        }
    }
}

// ---------------------------------------------------------------------------
// Kernel 3: accuracy = mean(adjusted_counts[b] < TOPK).
// ---------------------------------------------------------------------------
__global__ void finalize_kernel(const int* __restrict__ counts,
                                const float* __restrict__ s_t,
                                float* __restrict__ out,
                                int pad_correct) {
    __shared__ int sdata[4];
    int tid = threadIdx.x;
    int local = 0;
    for (int i = tid; i < B_ROWS; i += 256) {
        int c = counts[i];
        if (pad_correct && s_t[i] < 0.0f) c -= PADROWS;
        local += (c < TOPK) ? 1 : 0;
    }
    #pragma unroll
    for (int m = 1; m < 64; m <<= 1) local += __shfl_xor(local, m, 64);
    if ((tid & 63) == 0) sdata[tid >> 6] = local;
    __syncthreads();
    if (tid == 0)
        out[0] = (float)(sdata[0] + sdata[1] + sdata[2] + sdata[3]) /
                 (float)B_ROWS;
}

extern "C" void kernel_launch(void* const* d_in, const int* in_sizes, int n_in,
                              void* d_out, int out_size, void* d_ws, size_t ws_size,
                              hipStream_t stream) {
    const float* P      = (const float*)d_in[0];
    const float* Lab    = (const float*)d_in[1];
    const int*   labels = (const int*)d_in[2];
    float* out = (float*)d_out;

    float* s_t    = (float*)d_ws;
    int*   counts = (int*)((char*)d_ws + 16384);

    prep_kernel<<<dim3(B_ROWS / 4), 256, 0, stream>>>(P, Lab, labels, s_t, counts);

    const size_t pb_off = 32768;
    const size_t lb_off = pb_off + (size_t)B_ROWS * D_DIM * 2;  // 2 MB
    const size_t need   = lb_off + (size_t)L_PAD * D_DIM * 2;   // ~51 MB

    int fast = (ws_size >= need) ? 1 : 0;
    if (fast) {
        __hip_bfloat16* Pb = (__hip_bfloat16*)((char*)d_ws + pb_off);
        __hip_bfloat16* Lb = (__hip_bfloat16*)((char*)d_ws + lb_off);
        convertP_kernel<<<dim3((B_ROWS * D_DIM) / 2048), 256, 0, stream>>>(P, Pb);
        convertL_kernel<<<dim3(((size_t)L_PAD * D_DIM) / 2048), 256, 0, stream>>>(Lab, Lb);
        count_kernel_v6<<<dim3(NGROUP, B_ROWS / CBM), 512, 0, stream>>>(
            Pb, Lb, labels, s_t, counts);
    } else {
        dim3 grid((L_LABELS + FBN - 1) / FBN, B_ROWS / FBM);
        count_kernel_slow<<<grid, 256, 0, stream>>>(P, Lab, labels, s_t, counts);
    }

    finalize_kernel<<<1, 256, 0, stream>>>(counts, s_t, out, fast);
}